// Round 6
// baseline (3327.200 us; speedup 1.0000x reference)
//
#include <hip/hip_runtime.h>
#include <hip/hip_bf16.h>

// Mamba2 mixer forward, MI355X gfx950. Round 6: round-3 pipeline + f32 d_out
// (reference output dtype is float32 -> d_out is float*).
// Shapes fixed: B=2 L=4096 dm=1024 di=2048 H=16 ds=hd=128 cs=128
#define NB 2
#define LSEQ 4096
#define DM 1024
#define DI 2048
#define NH 16
#define DSZ 128
#define CS 128
#define NCHUNK 32

using bf16 = __hip_bfloat16;

__device__ __forceinline__ float b2f(unsigned short u) {
    union { unsigned i; float f; } c; c.i = ((unsigned)u) << 16; return c.f;
}
__device__ __forceinline__ bf16 f2bf(float v) { return __float2bfloat16(v); }
__device__ __forceinline__ float bf2f(bf16 v) { return __bfloat162float(v); }

__device__ __forceinline__ float head_dt(const float* dt_bias, int h) {
    return log1pf(expf(dt_bias[h]));               // softplus; input ~[-7,-2.2]
}
// log2(decay) = -exp(A_log[h]) * dt * log2(e);  finite for all heads (>= -2.4)
__device__ __forceinline__ float head_l2dec(const float* dt_bias, const float* A_log, int h, float* dt_out) {
    float dt = head_dt(dt_bias, h);
    *dt_out = dt;
    return -expf(A_log[h]) * dt * 1.4426950408889634f;
}

// ---------------- GEMM: C[m,n] = sum_k A[m,k]*Bw[n,k]; A MxK (f32 or bf16 ws), Bw NxK f32.
__device__ __forceinline__ void load4(const float* A, size_t off, float* o) {
    float4 v = *reinterpret_cast<const float4*>(A + off);
    o[0] = v.x; o[1] = v.y; o[2] = v.z; o[3] = v.w;
}
__device__ __forceinline__ void load4(const bf16* A, size_t off, float* o) {
    ushort4 u = *reinterpret_cast<const ushort4*>(A + off);
    o[0] = b2f(u.x); o[1] = b2f(u.y); o[2] = b2f(u.z); o[3] = b2f(u.w);
}
__device__ __forceinline__ void storeC(bf16* C, size_t idx, float v) { C[idx] = f2bf(v); }
__device__ __forceinline__ void storeC(float* C, size_t idx, float v) { C[idx] = v; }

// MODE 1: col<DI -> C0 (value), else C1 (gate). MODE 2: C0[m*N+n]. TO = output elem type.
template <int MODE, typename TA, typename TO>
__global__ __launch_bounds__(256) void gemm_nt(const TA* __restrict__ A,
                                               const float* __restrict__ Bw,
                                               TO* __restrict__ C0, TO* __restrict__ C1,
                                               int N, int Kd) {
    __shared__ float As[16][65];
    __shared__ float Bs[16][65];
    const int tid = threadIdx.x;
    const int tr = tid >> 4, tc = tid & 15;
    const int bm = blockIdx.y * 64;
    const int bn = blockIdx.x * 64;
    float acc[4][4] = {};
    for (int k0 = 0; k0 < Kd; k0 += 16) {
        {
            int r = tid >> 2;            // 0..63
            int kk = (tid & 3) << 2;     // 0,4,8,12
            float av[4], bv[4];
            load4(A, (size_t)(bm + r) * Kd + k0 + kk, av);
            load4(Bw, (size_t)(bn + r) * Kd + k0 + kk, bv);
#pragma unroll
            for (int t = 0; t < 4; ++t) { As[kk + t][r] = av[t]; Bs[kk + t][r] = bv[t]; }
        }
        __syncthreads();
#pragma unroll
        for (int k = 0; k < 16; ++k) {
            float a0 = As[k][tr], a1 = As[k][tr + 16], a2 = As[k][tr + 32], a3 = As[k][tr + 48];
            float b0 = Bs[k][tc], b1 = Bs[k][tc + 16], b2 = Bs[k][tc + 32], b3 = Bs[k][tc + 48];
            acc[0][0] += a0 * b0; acc[0][1] += a0 * b1; acc[0][2] += a0 * b2; acc[0][3] += a0 * b3;
            acc[1][0] += a1 * b0; acc[1][1] += a1 * b1; acc[1][2] += a1 * b2; acc[1][3] += a1 * b3;
            acc[2][0] += a2 * b0; acc[2][1] += a2 * b1; acc[2][2] += a2 * b2; acc[2][3] += a2 * b3;
            acc[3][0] += a3 * b0; acc[3][1] += a3 * b1; acc[3][2] += a3 * b2; acc[3][3] += a3 * b3;
        }
        __syncthreads();
    }
#pragma unroll
    for (int i = 0; i < 4; ++i)
#pragma unroll
        for (int j = 0; j < 4; ++j) {
            int row = bm + tr + 16 * i;
            int col = bn + tc + 16 * j;
            float v = acc[i][j];
            if (MODE == 1) {
                if (col < DI) storeC(C0, (size_t)row * DI + col, v);
                else          storeC(C1, (size_t)row * DI + col - DI, v);
            } else {
                storeC(C0, (size_t)row * N + col, v);
            }
        }
}

// ---------------- depthwise causal conv (K=4) + bias + SiLU : bf16 -> bf16
__global__ __launch_bounds__(256) void conv_silu_kernel(const bf16* __restrict__ vpre,
                                                        const float* __restrict__ cw,
                                                        const float* __restrict__ cb,
                                                        bf16* __restrict__ vpost) {
    size_t idx = (size_t)blockIdx.x * 256 + threadIdx.x;   // over NB*LSEQ*DI
    int c = (int)(idx & (DI - 1));
    size_t bl = idx >> 11;                                  // b*LSEQ + l
    int l = (int)(bl & (LSEQ - 1));
    float s = cb[c];
#pragma unroll
    for (int k = 0; k < 4; ++k) {
        if (l - 3 + k >= 0) s += cw[c * 4 + k] * bf2f(vpre[idx + (size_t)((long)(k - 3) * DI)]);
    }
    vpost[idx] = f2bf(s / (1.f + expf(-s)));
}

// ---------------- chunk kernels: grid = NCHUNK*NH per batch, bid = n*16+h
// Per-thread output tile: contiguous 8x8 at (r0, c0) = ((tid>>4)*8, (tid&15)*8).

// CBL[i,j] = (i>=j) ? dec^(i-j) * sum_s C[i,s]*B[j,s] : 0
__global__ __launch_bounds__(256) void chunk_cbl(const bf16* __restrict__ Bm, const bf16* __restrict__ Cm,
                                                 const float* __restrict__ dt_bias, const float* __restrict__ A_log,
                                                 bf16* __restrict__ CBL, int b0) {
    __shared__ float Ct[128][33];
    __shared__ float Bt[128][33];
    const int tid = threadIdx.x;
    const int h = blockIdx.x & 15, n = blockIdx.x >> 4;
    float dt; float l2d = head_l2dec(dt_bias, A_log, h, &dt);
    const size_t base = ((size_t)(b0 * LSEQ + n * CS)) * 2048 + (size_t)h * 128;
    const int r0 = (tid >> 4) * 8, c0 = (tid & 15) * 8;
    float acc[8][8] = {};
    for (int s0 = 0; s0 < 128; s0 += 32) {
        for (int e = tid; e < 128 * 32; e += 256) {
            int row = e >> 5, col = e & 31;
            Ct[row][col] = bf2f(Cm[base + (size_t)row * 2048 + (s0 + col)]);
            Bt[row][col] = bf2f(Bm[base + (size_t)row * 2048 + (s0 + col)]);
        }
        __syncthreads();
        for (int s = 0; s < 32; ++s) {
            float cv[8], bv[8];
#pragma unroll
            for (int ii = 0; ii < 8; ++ii) cv[ii] = Ct[r0 + ii][s];
#pragma unroll
            for (int jj = 0; jj < 8; ++jj) bv[jj] = Bt[c0 + jj][s];
#pragma unroll
            for (int ii = 0; ii < 8; ++ii)
#pragma unroll
                for (int jj = 0; jj < 8; ++jj) acc[ii][jj] += cv[ii] * bv[jj];
        }
        __syncthreads();
    }
    const size_t ob = (size_t)blockIdx.x * (CS * CS);
#pragma unroll
    for (int ii = 0; ii < 8; ++ii)
#pragma unroll
        for (int jj = 0; jj < 8; ++jj) {
            int i = r0 + ii, j = c0 + jj;
            float v = (i >= j) ? acc[ii][jj] * exp2f((float)(i - j) * l2d) : 0.f;
            CBL[ob + (size_t)i * 128 + j] = f2bf(v);
        }
}

// states[s,d] = sum_j (B[j,s]*dec^(127-j)) * (v[j,d]*dt)
__global__ __launch_bounds__(256) void chunk_states(const bf16* __restrict__ Bm, const bf16* __restrict__ vpost,
                                                    const float* __restrict__ dt_bias, const float* __restrict__ A_log,
                                                    bf16* __restrict__ ST, int b0) {
    __shared__ float Bt[32][129];
    __shared__ float Xt[32][129];
    const int tid = threadIdx.x;
    const int h = blockIdx.x & 15, n = blockIdx.x >> 4;
    float dt; float l2d = head_l2dec(dt_bias, A_log, h, &dt);
    const size_t base = ((size_t)(b0 * LSEQ + n * CS)) * 2048 + (size_t)h * 128;
    const int r0 = (tid >> 4) * 8, c0 = (tid & 15) * 8;   // (s, d) block
    float acc[8][8] = {};
    for (int jt = 0; jt < 128; jt += 32) {
        for (int e = tid; e < 32 * 128; e += 256) {
            int lj = e >> 7, col = e & 127;
            int jg = jt + lj;
            Bt[lj][col] = bf2f(Bm[base + (size_t)jg * 2048 + col]) * exp2f((float)(127 - jg) * l2d);
            Xt[lj][col] = bf2f(vpost[base + (size_t)jg * 2048 + col]) * dt;
        }
        __syncthreads();
        for (int lj = 0; lj < 32; ++lj) {
            float bv[8], xv[8];
#pragma unroll
            for (int ii = 0; ii < 8; ++ii) bv[ii] = Bt[lj][r0 + ii];
#pragma unroll
            for (int jj = 0; jj < 8; ++jj) xv[jj] = Xt[lj][c0 + jj];
#pragma unroll
            for (int ii = 0; ii < 8; ++ii)
#pragma unroll
                for (int jj = 0; jj < 8; ++jj) acc[ii][jj] += bv[ii] * xv[jj];
        }
        __syncthreads();
    }
    const size_t ob = (size_t)blockIdx.x * (DSZ * DSZ);
#pragma unroll
    for (int ii = 0; ii < 8; ++ii)
#pragma unroll
        for (int jj = 0; jj < 8; ++jj)
            ST[ob + (size_t)(r0 + ii) * 128 + (c0 + jj)] = f2bf(acc[ii][jj]);
}

// inter-chunk recurrence, in place (per batch): h[n] = sum_{j<n} cd^(n-1-j) states[j]
__global__ __launch_bounds__(256) void scan_kernel(bf16* __restrict__ ST,
                                                   const float* __restrict__ dt_bias,
                                                   const float* __restrict__ A_log) {
    const int q = blockIdx.x & 7;
    const int h = blockIdx.x >> 3;                 // 0..15
    float dt; float l2d = head_l2dec(dt_bias, A_log, h, &dt);
    float cd = exp2f(128.f * l2d);                 // may underflow to 0 (matches ref f32)
    const int tid = threadIdx.x;
    float r[8] = {};
    for (int n = 0; n < NCHUNK; ++n) {
        size_t base = ((size_t)(n * NH + h)) * (DSZ * DSZ) + (size_t)q * 2048;
#pragma unroll
        for (int e = 0; e < 8; ++e) {
            size_t idx = base + e * 256 + tid;
            float v = bf2f(ST[idx]);
            ST[idx] = f2bf(r[e]);
            r[e] = cd * r[e] + v;
        }
    }
}

// y = (CBL @ (v*dt) + (C @ h)*dec^(i+1) + D*v) * silu(gate), in-place over gate
__global__ __launch_bounds__(256) void chunk_yfused(const bf16* __restrict__ Cm, const bf16* __restrict__ CBL,
                                                    const bf16* __restrict__ ST, const bf16* __restrict__ vpost,
                                                    const float* __restrict__ dt_bias, const float* __restrict__ A_log,
                                                    const float* __restrict__ D_param,
                                                    bf16* __restrict__ gateY, int b0) {
    __shared__ float Tt[128][33];     // [row i][local k]
    __shared__ float Ut[32][129];     // [local k][col d]
    const int tid = threadIdx.x;
    const int h = blockIdx.x & 15, n = blockIdx.x >> 4;
    float dt; float l2d = head_l2dec(dt_bias, A_log, h, &dt);
    const size_t base = ((size_t)(b0 * LSEQ + n * CS)) * 2048 + (size_t)h * 128;
    const size_t ob = (size_t)blockIdx.x * (DSZ * DSZ);
    const int r0 = (tid >> 4) * 8, c0 = (tid & 15) * 8;
    float acc[8][8] = {};
    // phase A: acc[i,d] = sum_s C[i,s] * h[s,d]
    for (int s0 = 0; s0 < 128; s0 += 32) {
        for (int e = tid; e < 128 * 32; e += 256) {
            int row = e >> 5, col = e & 31;
            Tt[row][col] = bf2f(Cm[base + (size_t)row * 2048 + (s0 + col)]);
        }
        for (int e = tid; e < 32 * 128; e += 256) {
            int ls = e >> 7, col = e & 127;
            Ut[ls][col] = bf2f(ST[ob + (size_t)(s0 + ls) * 128 + col]);
        }
        __syncthreads();
        for (int k = 0; k < 32; ++k) {
            float tv[8], uv[8];
#pragma unroll
            for (int ii = 0; ii < 8; ++ii) tv[ii] = Tt[r0 + ii][k];
#pragma unroll
            for (int jj = 0; jj < 8; ++jj) uv[jj] = Ut[k][c0 + jj];
#pragma unroll
            for (int ii = 0; ii < 8; ++ii)
#pragma unroll
                for (int jj = 0; jj < 8; ++jj) acc[ii][jj] += tv[ii] * uv[jj];
        }
        __syncthreads();
    }
#pragma unroll
    for (int ii = 0; ii < 8; ++ii) {
        float sc = exp2f((float)(r0 + ii + 1) * l2d);   // decay_out[i] = dec^(i+1)
#pragma unroll
        for (int jj = 0; jj < 8; ++jj) acc[ii][jj] *= sc;
    }
    // phase B: acc[i,d] += sum_j CBL[i,j] * v[j,d]*dt
    for (int k0 = 0; k0 < 128; k0 += 32) {
        for (int e = tid; e < 128 * 32; e += 256) {
            int row = e >> 5, col = e & 31;
            Tt[row][col] = bf2f(CBL[ob + (size_t)row * 128 + (k0 + col)]);
        }
        for (int e = tid; e < 32 * 128; e += 256) {
            int lk = e >> 7, col = e & 127;
            Ut[lk][col] = bf2f(vpost[base + (size_t)(k0 + lk) * 2048 + col]) * dt;
        }
        __syncthreads();
        for (int k = 0; k < 32; ++k) {
            float tv[8], uv[8];
#pragma unroll
            for (int ii = 0; ii < 8; ++ii) tv[ii] = Tt[r0 + ii][k];
#pragma unroll
            for (int jj = 0; jj < 8; ++jj) uv[jj] = Ut[k][c0 + jj];
#pragma unroll
            for (int ii = 0; ii < 8; ++ii)
#pragma unroll
                for (int jj = 0; jj < 8; ++jj) acc[ii][jj] += tv[ii] * uv[jj];
        }
        __syncthreads();
    }
    // epilogue: y = (acc + D*v) * silu(gate)
    float Dv = D_param[h];
#pragma unroll
    for (int ii = 0; ii < 8; ++ii)
#pragma unroll
        for (int jj = 0; jj < 8; ++jj) {
            int i = r0 + ii, d = c0 + jj;
            size_t idx = base + (size_t)i * 2048 + d;
            float yv = acc[ii][jj] + Dv * bf2f(vpost[idx]);
            float g = bf2f(gateY[idx]);
            gateY[idx] = f2bf(yv * g / (1.f + expf(-g)));
        }
}

extern "C" void kernel_launch(void* const* d_in, const int* in_sizes, int n_in,
                              void* d_out, int out_size, void* d_ws, size_t ws_size,
                              hipStream_t stream) {
    (void)out_size;
    // input-order sentinel (verified passing in round 5)
    static const int exp_sizes[11] = {
        NB * LSEQ * DM, NB * LSEQ * DM, 2 * DI * DM, DI * 4, DI,
        NH * DSZ * DM, NH * DSZ * DM, NH, NH, NH, DM * DI
    };
    if (n_in != 11) return;
    for (int i = 0; i < 11; ++i) if (in_sizes[i] != exp_sizes[i]) return;

    const float* x         = (const float*)d_in[0];
    const float* x_prenorm = (const float*)d_in[1];
    const float* in_proj_w = (const float*)d_in[2];
    const float* conv_w    = (const float*)d_in[3];
    const float* conv_b    = (const float*)d_in[4];
    const float* B_proj_w  = (const float*)d_in[5];
    const float* C_proj_w  = (const float*)d_in[6];
    const float* dt_bias   = (const float*)d_in[7];
    const float* A_log     = (const float*)d_in[8];
    const float* D_param   = (const float*)d_in[9];
    const float* out_proj_w= (const float*)d_in[10];
    float* out = (float*)d_out;                     // reference output dtype = float32

    const size_t NE = (size_t)NB * LSEQ * DI;     // 16,777,216 elements
    const size_t SLOT = NE * 2;                   // 32 MiB
    if (ws_size < 5 * SLOT) return;               // 160 MiB (available: kernels ran r2-r5)
    char* ws = (char*)d_ws;
    bf16* S0 = (bf16*)(ws);              // value_pre; later per-batch {CBL | states}
    bf16* S1 = (bf16*)(ws + SLOT);       // gate; y written in-place
    bf16* S2 = (bf16*)(ws + 2 * SLOT);   // vpost
    bf16* S3 = (bf16*)(ws + 3 * SLOT);   // Bm
    bf16* S4 = (bf16*)(ws + 4 * SLOT);   // Cm
    const size_t HALF = NE / 2;          // per-batch 8,388,608 elems
    bf16* CBL = S0;                      // per-batch chunk scratch (value_pre dead post-conv)
    bf16* STT = S0 + HALF;

    const int M = NB * LSEQ;             // 8192
    dim3 blk(256);

    gemm_nt<1, float, bf16><<<dim3(2 * DI / 64, M / 64), blk, 0, stream>>>(x, in_proj_w, S0, S1, 2 * DI, DM);
    conv_silu_kernel<<<dim3((unsigned)(NE / 256)), blk, 0, stream>>>(S0, conv_w, conv_b, S2);
    gemm_nt<2, float, bf16><<<dim3(DI / 64, M / 64), blk, 0, stream>>>(x_prenorm, B_proj_w, S3, nullptr, DI, DM);
    gemm_nt<2, float, bf16><<<dim3(DI / 64, M / 64), blk, 0, stream>>>(x_prenorm, C_proj_w, S4, nullptr, DI, DM);

    for (int b0 = 0; b0 < NB; ++b0) {
        chunk_cbl<<<dim3(NCHUNK * NH), blk, 0, stream>>>(S3, S4, dt_bias, A_log, CBL, b0);
        chunk_states<<<dim3(NCHUNK * NH), blk, 0, stream>>>(S3, S2, dt_bias, A_log, STT, b0);
        scan_kernel<<<dim3(NH * 8), blk, 0, stream>>>(STT, dt_bias, A_log);
        chunk_yfused<<<dim3(NCHUNK * NH), blk, 0, stream>>>(S4, CBL, STT, S2, dt_bias, A_log, D_param, S1, b0);
    }
    // out_proj -> f32 d_out
    gemm_nt<2, bf16, float><<<dim3(DM / 64, M / 64), blk, 0, stream>>>(S1, out_proj_w, out, nullptr, DM, DI);
}

// Round 7
// 793.024 us; speedup vs baseline: 4.1956x; 4.1956x over previous
//
#include <hip/hip_runtime.h>
#include <hip/hip_bf16.h>

// Mamba2 mixer forward, MI355X gfx950. Round 7: bf16 MFMA projection GEMMs
// (m97-structure: 128x128 tile, BK=32, global_load_lds w16, double-buffered LDS).
// Chunk/conv/scan kernels frozen from round 6 (passing baseline).
// Shapes fixed: B=2 L=4096 dm=1024 di=2048 H=16 ds=hd=128 cs=128
#define NB 2
#define LSEQ 4096
#define DM 1024
#define DI 2048
#define NH 16
#define DSZ 128
#define CS 128
#define NCHUNK 32

using bf16 = __hip_bfloat16;
typedef __attribute__((ext_vector_type(8))) short short8;
typedef __attribute__((ext_vector_type(4))) float f32x4;

__device__ __forceinline__ float b2f(unsigned short u) {
    union { unsigned i; float f; } c; c.i = ((unsigned)u) << 16; return c.f;
}
__device__ __forceinline__ bf16 f2bf(float v) { return __float2bfloat16(v); }
__device__ __forceinline__ float bf2f(bf16 v) { return __bfloat162float(v); }

__device__ __forceinline__ float head_dt(const float* dt_bias, int h) {
    return log1pf(expf(dt_bias[h]));               // softplus
}
__device__ __forceinline__ float head_l2dec(const float* dt_bias, const float* A_log, int h, float* dt_out) {
    float dt = head_dt(dt_bias, h);
    *dt_out = dt;
    return -expf(A_log[h]) * dt * 1.4426950408889634f;   // log2(decay)
}

__device__ __forceinline__ void storeC(bf16* C, size_t idx, float v) { C[idx] = f2bf(v); }
__device__ __forceinline__ void storeC(float* C, size_t idx, float v) { C[idx] = v; }

// async global->LDS, 16B per lane; lds base must be wave-uniform (HW adds lane*16B)
__device__ __forceinline__ void gload16(const bf16* g, bf16* l) {
    __builtin_amdgcn_global_load_lds(
        (const __attribute__((address_space(1))) void*)g,
        (__attribute__((address_space(3))) void*)l, 16, 0, 0);
}

// ---------------- f32 -> bf16 cast (vectorized, 8 elems/thread)
__global__ __launch_bounds__(256) void cast_f2b(const float* __restrict__ in,
                                                bf16* __restrict__ out, long n) {
    long i = ((long)blockIdx.x * 256 + threadIdx.x) * 8;
    if (i >= n) return;
    float4 a = *reinterpret_cast<const float4*>(in + i);
    float4 b = *reinterpret_cast<const float4*>(in + i + 4);
    union { bf16 h[8]; short8 v; } o;
    o.h[0] = f2bf(a.x); o.h[1] = f2bf(a.y); o.h[2] = f2bf(a.z); o.h[3] = f2bf(a.w);
    o.h[4] = f2bf(b.x); o.h[5] = f2bf(b.y); o.h[6] = f2bf(b.z); o.h[7] = f2bf(b.w);
    *reinterpret_cast<short8*>(out + i) = o.v;
}

// ---------------- MFMA GEMM: C[m,n] = sum_k A[m,k]*W[n,k]; A MxK bf16, W NxK bf16.
// 128x128 tile, BK=32, 4 waves (2x2), per-wave 64x64 = 4x4 frags of 16x16x32.
// MODE 1 (N=4096): col<DI -> C0 (value), else C1 (gate). MODE 2: C0[m*N+n].
template <int MODE, typename TO>
__global__ __launch_bounds__(256) void gemm_mfma(const bf16* __restrict__ A,
                                                 const bf16* __restrict__ W,
                                                 TO* __restrict__ C0, TO* __restrict__ C1,
                                                 int N, int K) {
    __shared__ bf16 As[2][128 * 32];
    __shared__ bf16 Ws[2][128 * 32];
    const int tid = threadIdx.x;
    const int lane = tid & 63, w = tid >> 6;
    const int wr = w >> 1, wc = w & 1;
    const int bm = blockIdx.y * 128, bn = blockIdx.x * 128;

    // staging: wave w covers row-groups g0=2w, g1=2w+1 (16 rows x 32 k each = 1024B)
    const int srow = lane >> 2;            // 0..15
    const int skoff = (lane & 3) * 8;      // 0,8,16,24
    const int g0 = w * 2, g1 = w * 2 + 1;

    // fragment read coords
    const int fr = lane & 15, fk = (lane >> 4) * 8;

    f32x4 acc[4][4] = {};

#define STAGE(buf, kt)                                                                  \
    do {                                                                                \
        gload16(A + (size_t)(bm + g0 * 16 + srow) * K + (kt) + skoff, &As[buf][g0 * 512]); \
        gload16(A + (size_t)(bm + g1 * 16 + srow) * K + (kt) + skoff, &As[buf][g1 * 512]); \
        gload16(W + (size_t)(bn + g0 * 16 + srow) * K + (kt) + skoff, &Ws[buf][g0 * 512]); \
        gload16(W + (size_t)(bn + g1 * 16 + srow) * K + (kt) + skoff, &Ws[buf][g1 * 512]); \
    } while (0)

    STAGE(0, 0);
    __syncthreads();
    const int NT = K / 32;
    int cur = 0;
    for (int t = 0; t < NT; ++t) {
        if (t + 1 < NT) STAGE(cur ^ 1, (t + 1) * 32);
        short8 af[4], bfr[4];
#pragma unroll
        for (int mi = 0; mi < 4; ++mi)
            af[mi] = *reinterpret_cast<const short8*>(&As[cur][(wr * 64 + mi * 16 + fr) * 32 + fk]);
#pragma unroll
        for (int ni = 0; ni < 4; ++ni)
            bfr[ni] = *reinterpret_cast<const short8*>(&Ws[cur][(wc * 64 + ni * 16 + fr) * 32 + fk]);
#pragma unroll
        for (int mi = 0; mi < 4; ++mi)
#pragma unroll
            for (int ni = 0; ni < 4; ++ni)
                acc[mi][ni] = __builtin_amdgcn_mfma_f32_16x16x32_bf16(af[mi], bfr[ni], acc[mi][ni], 0, 0, 0);
        __syncthreads();
        cur ^= 1;
    }
#undef STAGE

    // epilogue: D frag mapping col=lane&15, row=(lane>>4)*4+reg
    const int orow0 = (lane >> 4) * 4;
    const int ocol = lane & 15;
#pragma unroll
    for (int mi = 0; mi < 4; ++mi)
#pragma unroll
        for (int ni = 0; ni < 4; ++ni) {
            int col = bn + wc * 64 + ni * 16 + ocol;
#pragma unroll
            for (int r = 0; r < 4; ++r) {
                int row = bm + wr * 64 + mi * 16 + orow0 + r;
                float v = acc[mi][ni][r];
                if (MODE == 1) {
                    if (col < DI) storeC(C0, (size_t)row * DI + col, v);
                    else          storeC(C1, (size_t)row * DI + (col - DI), v);
                } else {
                    storeC(C0, (size_t)row * N + col, v);
                }
            }
        }
}

// ---------------- depthwise causal conv (K=4) + bias + SiLU : bf16 -> bf16
__global__ __launch_bounds__(256) void conv_silu_kernel(const bf16* __restrict__ vpre,
                                                        const float* __restrict__ cw,
                                                        const float* __restrict__ cb,
                                                        bf16* __restrict__ vpost) {
    size_t idx = (size_t)blockIdx.x * 256 + threadIdx.x;   // over NB*LSEQ*DI
    int c = (int)(idx & (DI - 1));
    size_t bl = idx >> 11;                                  // b*LSEQ + l
    int l = (int)(bl & (LSEQ - 1));
    float s = cb[c];
#pragma unroll
    for (int k = 0; k < 4; ++k) {
        if (l - 3 + k >= 0) s += cw[c * 4 + k] * bf2f(vpre[idx + (size_t)((long)(k - 3) * DI)]);
    }
    vpost[idx] = f2bf(s / (1.f + expf(-s)));
}

// ---------------- chunk kernels (frozen from round 6): grid = NCHUNK*NH per batch
__global__ __launch_bounds__(256) void chunk_cbl(const bf16* __restrict__ Bm, const bf16* __restrict__ Cm,
                                                 const float* __restrict__ dt_bias, const float* __restrict__ A_log,
                                                 bf16* __restrict__ CBL, int b0) {
    __shared__ float Ct[128][33];
    __shared__ float Bt[128][33];
    const int tid = threadIdx.x;
    const int h = blockIdx.x & 15, n = blockIdx.x >> 4;
    float dt; float l2d = head_l2dec(dt_bias, A_log, h, &dt);
    const size_t base = ((size_t)(b0 * LSEQ + n * CS)) * 2048 + (size_t)h * 128;
    const int r0 = (tid >> 4) * 8, c0 = (tid & 15) * 8;
    float acc[8][8] = {};
    for (int s0 = 0; s0 < 128; s0 += 32) {
        for (int e = tid; e < 128 * 32; e += 256) {
            int row = e >> 5, col = e & 31;
            Ct[row][col] = bf2f(Cm[base + (size_t)row * 2048 + (s0 + col)]);
            Bt[row][col] = bf2f(Bm[base + (size_t)row * 2048 + (s0 + col)]);
        }
        __syncthreads();
        for (int s = 0; s < 32; ++s) {
            float cv[8], bv[8];
#pragma unroll
            for (int ii = 0; ii < 8; ++ii) cv[ii] = Ct[r0 + ii][s];
#pragma unroll
            for (int jj = 0; jj < 8; ++jj) bv[jj] = Bt[c0 + jj][s];
#pragma unroll
            for (int ii = 0; ii < 8; ++ii)
#pragma unroll
                for (int jj = 0; jj < 8; ++jj) acc[ii][jj] += cv[ii] * bv[jj];
        }
        __syncthreads();
    }
    const size_t ob = (size_t)blockIdx.x * (CS * CS);
#pragma unroll
    for (int ii = 0; ii < 8; ++ii)
#pragma unroll
        for (int jj = 0; jj < 8; ++jj) {
            int i = r0 + ii, j = c0 + jj;
            float v = (i >= j) ? acc[ii][jj] * exp2f((float)(i - j) * l2d) : 0.f;
            CBL[ob + (size_t)i * 128 + j] = f2bf(v);
        }
}

__global__ __launch_bounds__(256) void chunk_states(const bf16* __restrict__ Bm, const bf16* __restrict__ vpost,
                                                    const float* __restrict__ dt_bias, const float* __restrict__ A_log,
                                                    bf16* __restrict__ ST, int b0) {
    __shared__ float Bt[32][129];
    __shared__ float Xt[32][129];
    const int tid = threadIdx.x;
    const int h = blockIdx.x & 15, n = blockIdx.x >> 4;
    float dt; float l2d = head_l2dec(dt_bias, A_log, h, &dt);
    const size_t base = ((size_t)(b0 * LSEQ + n * CS)) * 2048 + (size_t)h * 128;
    const int r0 = (tid >> 4) * 8, c0 = (tid & 15) * 8;
    float acc[8][8] = {};
    for (int jt = 0; jt < 128; jt += 32) {
        for (int e = tid; e < 32 * 128; e += 256) {
            int lj = e >> 7, col = e & 127;
            int jg = jt + lj;
            Bt[lj][col] = bf2f(Bm[base + (size_t)jg * 2048 + col]) * exp2f((float)(127 - jg) * l2d);
            Xt[lj][col] = bf2f(vpost[base + (size_t)jg * 2048 + col]) * dt;
        }
        __syncthreads();
        for (int lj = 0; lj < 32; ++lj) {
            float bv[8], xv[8];
#pragma unroll
            for (int ii = 0; ii < 8; ++ii) bv[ii] = Bt[lj][r0 + ii];
#pragma unroll
            for (int jj = 0; jj < 8; ++jj) xv[jj] = Xt[lj][c0 + jj];
#pragma unroll
            for (int ii = 0; ii < 8; ++ii)
#pragma unroll
                for (int jj = 0; jj < 8; ++jj) acc[ii][jj] += bv[ii] * xv[jj];
        }
        __syncthreads();
    }
    const size_t ob = (size_t)blockIdx.x * (DSZ * DSZ);
#pragma unroll
    for (int ii = 0; ii < 8; ++ii)
#pragma unroll
        for (int jj = 0; jj < 8; ++jj)
            ST[ob + (size_t)(r0 + ii) * 128 + (c0 + jj)] = f2bf(acc[ii][jj]);
}

__global__ __launch_bounds__(256) void scan_kernel(bf16* __restrict__ ST,
                                                   const float* __restrict__ dt_bias,
                                                   const float* __restrict__ A_log) {
    const int q = blockIdx.x & 7;
    const int h = blockIdx.x >> 3;
    float dt; float l2d = head_l2dec(dt_bias, A_log, h, &dt);
    float cd = exp2f(128.f * l2d);
    const int tid = threadIdx.x;
    float r[8] = {};
    for (int n = 0; n < NCHUNK; ++n) {
        size_t base = ((size_t)(n * NH + h)) * (DSZ * DSZ) + (size_t)q * 2048;
#pragma unroll
        for (int e = 0; e < 8; ++e) {
            size_t idx = base + e * 256 + tid;
            float v = bf2f(ST[idx]);
            ST[idx] = f2bf(r[e]);
            r[e] = cd * r[e] + v;
        }
    }
}

__global__ __launch_bounds__(256) void chunk_yfused(const bf16* __restrict__ Cm, const bf16* __restrict__ CBL,
                                                    const bf16* __restrict__ ST, const bf16* __restrict__ vpost,
                                                    const float* __restrict__ dt_bias, const float* __restrict__ A_log,
                                                    const float* __restrict__ D_param,
                                                    bf16* __restrict__ gateY, int b0) {
    __shared__ float Tt[128][33];
    __shared__ float Ut[32][129];
    const int tid = threadIdx.x;
    const int h = blockIdx.x & 15, n = blockIdx.x >> 4;
    float dt; float l2d = head_l2dec(dt_bias, A_log, h, &dt);
    const size_t base = ((size_t)(b0 * LSEQ + n * CS)) * 2048 + (size_t)h * 128;
    const size_t ob = (size_t)blockIdx.x * (DSZ * DSZ);
    const int r0 = (tid >> 4) * 8, c0 = (tid & 15) * 8;
    float acc[8][8] = {};
    for (int s0 = 0; s0 < 128; s0 += 32) {
        for (int e = tid; e < 128 * 32; e += 256) {
            int row = e >> 5, col = e & 31;
            Tt[row][col] = bf2f(Cm[base + (size_t)row * 2048 + (s0 + col)]);
        }
        for (int e = tid; e < 32 * 128; e += 256) {
            int ls = e >> 7, col = e & 127;
            Ut[ls][col] = bf2f(ST[ob + (size_t)(s0 + ls) * 128 + col]);
        }
        __syncthreads();
        for (int k = 0; k < 32; ++k) {
            float tv[8], uv[8];
#pragma unroll
            for (int ii = 0; ii < 8; ++ii) tv[ii] = Tt[r0 + ii][k];
#pragma unroll
            for (int jj = 0; jj < 8; ++jj) uv[jj] = Ut[k][c0 + jj];
#pragma unroll
            for (int ii = 0; ii < 8; ++ii)
#pragma unroll
                for (int jj = 0; jj < 8; ++jj) acc[ii][jj] += tv[ii] * uv[jj];
        }
        __syncthreads();
    }
#pragma unroll
    for (int ii = 0; ii < 8; ++ii) {
        float sc = exp2f((float)(r0 + ii + 1) * l2d);
#pragma unroll
        for (int jj = 0; jj < 8; ++jj) acc[ii][jj] *= sc;
    }
    for (int k0 = 0; k0 < 128; k0 += 32) {
        for (int e = tid; e < 128 * 32; e += 256) {
            int row = e >> 5, col = e & 31;
            Tt[row][col] = bf2f(CBL[ob + (size_t)row * 128 + (k0 + col)]);
        }
        for (int e = tid; e < 32 * 128; e += 256) {
            int lk = e >> 7, col = e & 127;
            Ut[lk][col] = bf2f(vpost[base + (size_t)(k0 + lk) * 2048 + col]) * dt;
        }
        __syncthreads();
        for (int k = 0; k < 32; ++k) {
            float tv[8], uv[8];
#pragma unroll
            for (int ii = 0; ii < 8; ++ii) tv[ii] = Tt[r0 + ii][k];
#pragma unroll
            for (int jj = 0; jj < 8; ++jj) uv[jj] = Ut[k][c0 + jj];
#pragma unroll
            for (int ii = 0; ii < 8; ++ii)
#pragma unroll
                for (int jj = 0; jj < 8; ++jj) acc[ii][jj] += tv[ii] * uv[jj];
        }
        __syncthreads();
    }
    float Dv = D_param[h];
#pragma unroll
    for (int ii = 0; ii < 8; ++ii)
#pragma unroll
        for (int jj = 0; jj < 8; ++jj) {
            int i = r0 + ii, d = c0 + jj;
            size_t idx = base + (size_t)i * 2048 + d;
            float yv = acc[ii][jj] + Dv * bf2f(vpost[idx]);
            float g = bf2f(gateY[idx]);
            gateY[idx] = f2bf(yv * g / (1.f + expf(-g)));
        }
}

extern "C" void kernel_launch(void* const* d_in, const int* in_sizes, int n_in,
                              void* d_out, int out_size, void* d_ws, size_t ws_size,
                              hipStream_t stream) {
    (void)out_size;
    static const int exp_sizes[11] = {
        NB * LSEQ * DM, NB * LSEQ * DM, 2 * DI * DM, DI * 4, DI,
        NH * DSZ * DM, NH * DSZ * DM, NH, NH, NH, DM * DI
    };
    if (n_in != 11) return;
    for (int i = 0; i < 11; ++i) if (in_sizes[i] != exp_sizes[i]) return;

    const float* x         = (const float*)d_in[0];
    const float* x_prenorm = (const float*)d_in[1];
    const float* in_proj_w = (const float*)d_in[2];
    const float* conv_w    = (const float*)d_in[3];
    const float* conv_b    = (const float*)d_in[4];
    const float* B_proj_w  = (const float*)d_in[5];
    const float* C_proj_w  = (const float*)d_in[6];
    const float* dt_bias   = (const float*)d_in[7];
    const float* A_log     = (const float*)d_in[8];
    const float* D_param   = (const float*)d_in[9];
    const float* out_proj_w= (const float*)d_in[10];
    float* out = (float*)d_out;

    const size_t NE = (size_t)NB * LSEQ * DI;     // 16,777,216 elements
    const size_t SLOT = NE * 2;                   // 32 MiB
    if (ws_size < 5 * SLOT) return;               // 160 MiB (verified available)
    char* ws = (char*)d_ws;
    bf16* S0 = (bf16*)(ws);              // value_pre; later per-batch {CBL | states}
    bf16* S1 = (bf16*)(ws + SLOT);       // gate; y written in-place
    bf16* S2 = (bf16*)(ws + 2 * SLOT);   // vpost
    bf16* S3 = (bf16*)(ws + 3 * SLOT);   // w_in_b -> Bm -> w_out_b
    bf16* S4 = (bf16*)(ws + 4 * SLOT);   // Cm
    const size_t HALF = NE / 2;
    bf16* CBL = S0;
    bf16* STT = S0 + HALF;

    // d_out used as scratch until the final GEMM overwrites it:
    bf16* xb  = (bf16*)d_out;                          // x / x_prenorm bf16 (16.8 MB)
    bf16* wBb = (bf16*)((char*)d_out + 16777216);      // B_proj_w bf16 (4 MB)
    bf16* wCb = (bf16*)((char*)d_out + 20971520);      // C_proj_w bf16 (4 MB)
    bf16* wIb = S3;                                    // in_proj_w bf16 (8 MB, dead before Bm)
    bf16* wOb = S3;                                    // out_proj_w bf16 (after chunk loop)

    const int M = NB * LSEQ;             // 8192
    dim3 blk(256);

    // phase 1: in_proj (MFMA)
    cast_f2b<<<dim3(4096), blk, 0, stream>>>(x, xb, (long)NB * LSEQ * DM);
    cast_f2b<<<dim3(2048), blk, 0, stream>>>(in_proj_w, wIb, (long)2 * DI * DM);
    gemm_mfma<1, bf16><<<dim3(2 * DI / 128, M / 128), blk, 0, stream>>>(xb, wIb, S0, S1, 2 * DI, DM);
    // phase 2: conv + SiLU
    conv_silu_kernel<<<dim3((unsigned)(NE / 256)), blk, 0, stream>>>(S0, conv_w, conv_b, S2);
    // phase 3/4: B/C projections (MFMA)
    cast_f2b<<<dim3(4096), blk, 0, stream>>>(x_prenorm, xb, (long)NB * LSEQ * DM);
    cast_f2b<<<dim3(1024), blk, 0, stream>>>(B_proj_w, wBb, (long)NH * DSZ * DM);
    cast_f2b<<<dim3(1024), blk, 0, stream>>>(C_proj_w, wCb, (long)NH * DSZ * DM);
    gemm_mfma<2, bf16><<<dim3(DI / 128, M / 128), blk, 0, stream>>>(xb, wBb, S3, nullptr, DI, DM);
    gemm_mfma<2, bf16><<<dim3(DI / 128, M / 128), blk, 0, stream>>>(xb, wCb, S4, nullptr, DI, DM);
    // phase 5: chunked scan (frozen)
    for (int b0 = 0; b0 < NB; ++b0) {
        chunk_cbl<<<dim3(NCHUNK * NH), blk, 0, stream>>>(S3, S4, dt_bias, A_log, CBL, b0);
        chunk_states<<<dim3(NCHUNK * NH), blk, 0, stream>>>(S3, S2, dt_bias, A_log, STT, b0);
        scan_kernel<<<dim3(NH * 8), blk, 0, stream>>>(STT, dt_bias, A_log);
        chunk_yfused<<<dim3(NCHUNK * NH), blk, 0, stream>>>(S4, CBL, STT, S2, dt_bias, A_log, D_param, S1, b0);
    }
    // phase 6: out_proj (MFMA) -> f32 d_out
    cast_f2b<<<dim3(1024), blk, 0, stream>>>(out_proj_w, wOb, (long)DM * DI);
    gemm_mfma<2, float><<<dim3(DM / 128, M / 128), blk, 0, stream>>>(S1, wOb, out, nullptr, DM, DI);
}

// Round 8
// 491.372 us; speedup vs baseline: 6.7712x; 1.6139x over previous
//
#include <hip/hip_runtime.h>
#include <hip/hip_bf16.h>

// Mamba2 mixer forward, MI355X gfx950. Round 8: chunk phase moved to MFMA.
// Pre-transposed XDT/BT in HBM -> all LDS staging is vector; operand layouts
// copied from the round-7-verified gemm_mfma convention.
// Shapes fixed: B=2 L=4096 dm=1024 di=2048 H=16 ds=hd=128 cs=128
#define NB 2
#define LSEQ 4096
#define DM 1024
#define DI 2048
#define NH 16
#define DSZ 128
#define CS 128
#define NCHUNK 32

using bf16 = __hip_bfloat16;
typedef __attribute__((ext_vector_type(8))) short short8;
typedef __attribute__((ext_vector_type(4))) float f32x4;

__device__ __forceinline__ float b2f(unsigned short u) {
    union { unsigned i; float f; } c; c.i = ((unsigned)u) << 16; return c.f;
}
__device__ __forceinline__ bf16 f2bf(float v) { return __float2bfloat16(v); }
__device__ __forceinline__ float bf2f(bf16 v) { return __bfloat162float(v); }

__device__ __forceinline__ float head_dt(const float* dt_bias, int h) {
    return log1pf(expf(dt_bias[h]));               // softplus
}
__device__ __forceinline__ float head_l2dec(const float* dt_bias, const float* A_log, int h, float* dt_out) {
    float dt = head_dt(dt_bias, h);
    *dt_out = dt;
    return -expf(A_log[h]) * dt * 1.4426950408889634f;   // log2(decay)
}

__device__ __forceinline__ void storeC(bf16* C, size_t idx, float v) { C[idx] = f2bf(v); }
__device__ __forceinline__ void storeC(float* C, size_t idx, float v) { C[idx] = v; }

// async global->LDS, 16B per lane; lds base wave-uniform (HW adds lane*16B)
__device__ __forceinline__ void gload16(const bf16* g, bf16* l) {
    __builtin_amdgcn_global_load_lds(
        (const __attribute__((address_space(1))) void*)g,
        (__attribute__((address_space(3))) void*)l, 16, 0, 0);
}

// ---------------- f32 -> bf16 cast
__global__ __launch_bounds__(256) void cast_f2b(const float* __restrict__ in,
                                                bf16* __restrict__ out, long n) {
    long i = ((long)blockIdx.x * 256 + threadIdx.x) * 8;
    if (i >= n) return;
    float4 a = *reinterpret_cast<const float4*>(in + i);
    float4 b = *reinterpret_cast<const float4*>(in + i + 4);
    union { bf16 h[8]; short8 v; } o;
    o.h[0] = f2bf(a.x); o.h[1] = f2bf(a.y); o.h[2] = f2bf(a.z); o.h[3] = f2bf(a.w);
    o.h[4] = f2bf(b.x); o.h[5] = f2bf(b.y); o.h[6] = f2bf(b.z); o.h[7] = f2bf(b.w);
    *reinterpret_cast<short8*>(out + i) = o.v;
}

// ---------------- MFMA GEMM (frozen from round 7, verified)
template <int MODE, typename TO>
__global__ __launch_bounds__(256) void gemm_mfma(const bf16* __restrict__ A,
                                                 const bf16* __restrict__ W,
                                                 TO* __restrict__ C0, TO* __restrict__ C1,
                                                 int N, int K) {
    __shared__ bf16 As[2][128 * 32];
    __shared__ bf16 Ws[2][128 * 32];
    const int tid = threadIdx.x;
    const int lane = tid & 63, w = tid >> 6;
    const int wr = w >> 1, wc = w & 1;
    const int bm = blockIdx.y * 128, bn = blockIdx.x * 128;
    const int srow = lane >> 2;
    const int skoff = (lane & 3) * 8;
    const int g0 = w * 2, g1 = w * 2 + 1;
    const int fr = lane & 15, fk = (lane >> 4) * 8;
    f32x4 acc[4][4] = {};
#define STAGE(buf, kt)                                                                  \
    do {                                                                                \
        gload16(A + (size_t)(bm + g0 * 16 + srow) * K + (kt) + skoff, &As[buf][g0 * 512]); \
        gload16(A + (size_t)(bm + g1 * 16 + srow) * K + (kt) + skoff, &As[buf][g1 * 512]); \
        gload16(W + (size_t)(bn + g0 * 16 + srow) * K + (kt) + skoff, &Ws[buf][g0 * 512]); \
        gload16(W + (size_t)(bn + g1 * 16 + srow) * K + (kt) + skoff, &Ws[buf][g1 * 512]); \
    } while (0)
    STAGE(0, 0);
    __syncthreads();
    const int NT = K / 32;
    int cur = 0;
    for (int t = 0; t < NT; ++t) {
        if (t + 1 < NT) STAGE(cur ^ 1, (t + 1) * 32);
        short8 af[4], bfr[4];
#pragma unroll
        for (int mi = 0; mi < 4; ++mi)
            af[mi] = *reinterpret_cast<const short8*>(&As[cur][(wr * 64 + mi * 16 + fr) * 32 + fk]);
#pragma unroll
        for (int ni = 0; ni < 4; ++ni)
            bfr[ni] = *reinterpret_cast<const short8*>(&Ws[cur][(wc * 64 + ni * 16 + fr) * 32 + fk]);
#pragma unroll
        for (int mi = 0; mi < 4; ++mi)
#pragma unroll
            for (int ni = 0; ni < 4; ++ni)
                acc[mi][ni] = __builtin_amdgcn_mfma_f32_16x16x32_bf16(af[mi], bfr[ni], acc[mi][ni], 0, 0, 0);
        __syncthreads();
        cur ^= 1;
    }
#undef STAGE
    const int orow0 = (lane >> 4) * 4;
    const int ocol = lane & 15;
#pragma unroll
    for (int mi = 0; mi < 4; ++mi)
#pragma unroll
        for (int ni = 0; ni < 4; ++ni) {
            int col = bn + wc * 64 + ni * 16 + ocol;
#pragma unroll
            for (int r = 0; r < 4; ++r) {
                int row = bm + wr * 64 + mi * 16 + orow0 + r;
                float v = acc[mi][ni][r];
                if (MODE == 1) {
                    if (col < DI) storeC(C0, (size_t)row * DI + col, v);
                    else          storeC(C1, (size_t)row * DI + (col - DI), v);
                } else {
                    storeC(C0, (size_t)row * N + col, v);
                }
            }
        }
}

// ---------------- depthwise causal conv (K=4) + bias + SiLU (frozen)
__global__ __launch_bounds__(256) void conv_silu_kernel(const bf16* __restrict__ vpre,
                                                        const float* __restrict__ cw,
                                                        const float* __restrict__ cb,
                                                        bf16* __restrict__ vpost) {
    size_t idx = (size_t)blockIdx.x * 256 + threadIdx.x;
    int c = (int)(idx & (DI - 1));
    size_t bl = idx >> 11;
    int l = (int)(bl & (LSEQ - 1));
    float s = cb[c];
#pragma unroll
    for (int k = 0; k < 4; ++k) {
        if (l - 3 + k >= 0) s += cw[c * 4 + k] * bf2f(vpre[idx + (size_t)((long)(k - 3) * DI)]);
    }
    vpost[idx] = f2bf(s / (1.f + expf(-s)));
}

// ---------------- per-chunk 128x128 transpose (+scale). bid = (b*32+n)*16+h
// SCALEMODE 0: out[d][j] = in[j,d]*dt       (XDT)
// SCALEMODE 1: out[s][j] = in[j,s]*dec^(127-j)  (BT)
template <int SCALEMODE>
__global__ __launch_bounds__(256) void transpose_chunk(const bf16* __restrict__ in, bf16* __restrict__ outp,
                                                       const float* __restrict__ dt_bias,
                                                       const float* __restrict__ A_log) {
    __shared__ bf16 Ts[128][136];
    __shared__ float dpow[128];
    const int tid = threadIdx.x;
    const int bid = blockIdx.x;
    const int h = bid & 15, bn = bid >> 4;
    float dt; float l2d = head_l2dec(dt_bias, A_log, h, &dt);
    if (SCALEMODE == 1 && tid < 128) dpow[tid] = exp2f((float)(127 - tid) * l2d);
    const size_t base = (size_t)bn * CS * 2048 + (size_t)h * 128;
    {
        const int jr = tid >> 4, c8 = (tid & 15) * 8;
        for (int j0 = 0; j0 < 128; j0 += 16)
            *reinterpret_cast<short8*>(&Ts[j0 + jr][c8]) =
                *reinterpret_cast<const short8*>(in + base + (size_t)(j0 + jr) * 2048 + c8);
    }
    __syncthreads();
    const size_t ob = (size_t)bid * 16384;
    const int d = tid & 127;
    for (int jg = (tid >> 7); jg < 16; jg += 2) {
        int j0 = jg * 8;
        union { bf16 h8[8]; short8 v; } o;
#pragma unroll
        for (int e = 0; e < 8; ++e) {
            float val = bf2f(Ts[j0 + e][d]);
            val *= (SCALEMODE == 1) ? dpow[j0 + e] : dt;
            o.h8[e] = f2bf(val);
        }
        *reinterpret_cast<short8*>(outp + ob + (size_t)d * 128 + j0) = o.v;
    }
}

// ---------------- K1: STT[d][s] = sum_j XDT[d][j] * BT[s][j]  (MFMA, per chunk)
__global__ __launch_bounds__(256) void chunk_statesT(const bf16* __restrict__ XDT,
                                                     const bf16* __restrict__ BTg,
                                                     bf16* __restrict__ STT) {
    __shared__ bf16 XTs[128][72];
    __shared__ bf16 BTs[128][72];
    const int tid = threadIdx.x;
    const size_t ob = (size_t)blockIdx.x * 16384;
    const int lane = tid & 63, w = tid >> 6;
    const int fr = lane & 15, fk = (lane >> 4) * 8;
    f32x4 acc[2][8] = {};
    for (int j0 = 0; j0 < 128; j0 += 64) {
        for (int rr = 0; rr < 128; rr += 32) {
            int row = rr + (tid >> 3);
            int col = (tid & 7) * 8;
            *reinterpret_cast<short8*>(&XTs[row][col]) =
                *reinterpret_cast<const short8*>(XDT + ob + (size_t)row * 128 + j0 + col);
            *reinterpret_cast<short8*>(&BTs[row][col]) =
                *reinterpret_cast<const short8*>(BTg + ob + (size_t)row * 128 + j0 + col);
        }
        __syncthreads();
#pragma unroll
        for (int ks = 0; ks < 2; ++ks) {
            short8 a[2], bfr[8];
#pragma unroll
            for (int mi = 0; mi < 2; ++mi)
                a[mi] = *reinterpret_cast<const short8*>(&XTs[w * 32 + mi * 16 + fr][ks * 32 + fk]);
#pragma unroll
            for (int ni = 0; ni < 8; ++ni)
                bfr[ni] = *reinterpret_cast<const short8*>(&BTs[ni * 16 + fr][ks * 32 + fk]);
#pragma unroll
            for (int mi = 0; mi < 2; ++mi)
#pragma unroll
                for (int ni = 0; ni < 8; ++ni)
                    acc[mi][ni] = __builtin_amdgcn_mfma_f32_16x16x32_bf16(a[mi], bfr[ni], acc[mi][ni], 0, 0, 0);
        }
        __syncthreads();
    }
    const int orow0 = (lane >> 4) * 4, ocol = lane & 15;
#pragma unroll
    for (int mi = 0; mi < 2; ++mi)
#pragma unroll
        for (int ni = 0; ni < 8; ++ni) {
            int s = ni * 16 + ocol;
#pragma unroll
            for (int r = 0; r < 4; ++r) {
                int d = w * 32 + mi * 16 + orow0 + r;
                STT[ob + (size_t)d * 128 + s] = f2bf(acc[mi][ni][r]);
            }
        }
}

// ---------------- inter-chunk recurrence on STT (merged batches), in place
__global__ __launch_bounds__(256) void scan_kernel(bf16* __restrict__ ST,
                                                   const float* __restrict__ dt_bias,
                                                   const float* __restrict__ A_log) {
    const int q = blockIdx.x & 7;
    const int h = (blockIdx.x >> 3) & 15;
    const int b = blockIdx.x >> 7;
    float dt; float l2d = head_l2dec(dt_bias, A_log, h, &dt);
    float cd = exp2f(128.f * l2d);
    const int tid = threadIdx.x;
    float r[8] = {};
    for (int n = 0; n < NCHUNK; ++n) {
        size_t base = ((size_t)((b * NCHUNK + n) * NH + h)) * 16384 + (size_t)q * 2048;
#pragma unroll
        for (int e = 0; e < 8; ++e) {
            size_t idx = base + e * 256 + tid;
            float v = bf2f(ST[idx]);
            ST[idx] = f2bf(r[e]);
            r[e] = cd * r[e] + v;
        }
    }
}

// ---------------- K2a: P[i][j] = (i>=j)? dec^(i-j) * sum_s C[i,s]*B[j,s] : 0  (MFMA)
__global__ __launch_bounds__(256) void chunk_cbl_mfma(const bf16* __restrict__ Bm, const bf16* __restrict__ Cm,
                                                      const float* __restrict__ dt_bias,
                                                      const float* __restrict__ A_log,
                                                      bf16* __restrict__ P) {
    __shared__ bf16 Cs[128][72];
    __shared__ bf16 Bs[128][72];
    const int tid = threadIdx.x;
    const int bid = blockIdx.x;
    const int h = bid & 15, bn = bid >> 4;
    float dt; float l2d = head_l2dec(dt_bias, A_log, h, &dt);
    const size_t base = (size_t)bn * CS * 2048 + (size_t)h * 128;
    const int lane = tid & 63, w = tid >> 6;
    const int fr = lane & 15, fk = (lane >> 4) * 8;
    f32x4 acc[2][8] = {};
    for (int s0 = 0; s0 < 128; s0 += 64) {
        for (int rr = 0; rr < 128; rr += 32) {
            int row = rr + (tid >> 3);
            int col = (tid & 7) * 8;
            *reinterpret_cast<short8*>(&Cs[row][col]) =
                *reinterpret_cast<const short8*>(Cm + base + (size_t)row * 2048 + s0 + col);
            *reinterpret_cast<short8*>(&Bs[row][col]) =
                *reinterpret_cast<const short8*>(Bm + base + (size_t)row * 2048 + s0 + col);
        }
        __syncthreads();
#pragma unroll
        for (int ks = 0; ks < 2; ++ks) {
            short8 a[2], bfr[8];
#pragma unroll
            for (int mi = 0; mi < 2; ++mi)
                a[mi] = *reinterpret_cast<const short8*>(&Cs[w * 32 + mi * 16 + fr][ks * 32 + fk]);
#pragma unroll
            for (int ni = 0; ni < 8; ++ni)
                bfr[ni] = *reinterpret_cast<const short8*>(&Bs[ni * 16 + fr][ks * 32 + fk]);
#pragma unroll
            for (int mi = 0; mi < 2; ++mi)
#pragma unroll
                for (int ni = 0; ni < 8; ++ni)
                    acc[mi][ni] = __builtin_amdgcn_mfma_f32_16x16x32_bf16(a[mi], bfr[ni], acc[mi][ni], 0, 0, 0);
        }
        __syncthreads();
    }
    const size_t ob = (size_t)bid * 16384;
    const int orow0 = (lane >> 4) * 4, ocol = lane & 15;
#pragma unroll
    for (int mi = 0; mi < 2; ++mi)
#pragma unroll
        for (int ni = 0; ni < 8; ++ni) {
            int j = ni * 16 + ocol;
#pragma unroll
            for (int r = 0; r < 4; ++r) {
                int i = w * 32 + mi * 16 + orow0 + r;
                float v = (i >= j) ? acc[mi][ni][r] * exp2f((float)(i - j) * l2d) : 0.f;
                P[ob + (size_t)i * 128 + j] = f2bf(v);
            }
        }
}

// ---------------- K2b: y = P@XDT^T' + (C@h^T)*dec^(i+1) + D*v, *silu(gate)
__global__ __launch_bounds__(256) void chunk_y_mfma(const bf16* __restrict__ P, const bf16* __restrict__ Cm,
                                                    const bf16* __restrict__ STT, const bf16* __restrict__ XDT,
                                                    const float* __restrict__ dt_bias,
                                                    const float* __restrict__ A_log,
                                                    const float* __restrict__ D_param,
                                                    bf16* __restrict__ gateY) {
    __shared__ bf16 Ps[128][72];
    __shared__ bf16 XTs[128][72];
    const int tid = threadIdx.x;
    const int bid = blockIdx.x;
    const int h = bid & 15, bn = bid >> 4;
    float dt; float l2d = head_l2dec(dt_bias, A_log, h, &dt);
    const size_t base = (size_t)bn * CS * 2048 + (size_t)h * 128;
    const size_t ob = (size_t)bid * 16384;
    const int lane = tid & 63, w = tid >> 6;
    const int fr = lane & 15, fk = (lane >> 4) * 8;
    const int orow0 = (lane >> 4) * 4, ocol = lane & 15;
    f32x4 acc[2][8] = {};
    // phase 1: y2 = C @ h^T (direct-global frags; STT L2-hot from scan)
#pragma unroll
    for (int ks = 0; ks < 4; ++ks) {
        short8 a[2], bfr[8];
#pragma unroll
        for (int mi = 0; mi < 2; ++mi)
            a[mi] = *reinterpret_cast<const short8*>(Cm + base + (size_t)(w * 32 + mi * 16 + fr) * 2048 + ks * 32 + fk);
#pragma unroll
        for (int ni = 0; ni < 8; ++ni)
            bfr[ni] = *reinterpret_cast<const short8*>(STT + ob + (size_t)(ni * 16 + fr) * 128 + ks * 32 + fk);
#pragma unroll
        for (int mi = 0; mi < 2; ++mi)
#pragma unroll
            for (int ni = 0; ni < 8; ++ni)
                acc[mi][ni] = __builtin_amdgcn_mfma_f32_16x16x32_bf16(a[mi], bfr[ni], acc[mi][ni], 0, 0, 0);
    }
    // scale by decay_out = dec^(i+1)
#pragma unroll
    for (int mi = 0; mi < 2; ++mi)
#pragma unroll
        for (int r = 0; r < 4; ++r) {
            int i = w * 32 + mi * 16 + orow0 + r;
            float sc = exp2f((float)(i + 1) * l2d);
#pragma unroll
            for (int ni = 0; ni < 8; ++ni) acc[mi][ni][r] *= sc;
        }
    // phase 2: y += P @ xdt   (A-op P natural, B-op XDT natural)
    for (int j0 = 0; j0 < 128; j0 += 64) {
        for (int rr = 0; rr < 128; rr += 32) {
            int row = rr + (tid >> 3);
            int col = (tid & 7) * 8;
            *reinterpret_cast<short8*>(&Ps[row][col]) =
                *reinterpret_cast<const short8*>(P + ob + (size_t)row * 128 + j0 + col);
            *reinterpret_cast<short8*>(&XTs[row][col]) =
                *reinterpret_cast<const short8*>(XDT + ob + (size_t)row * 128 + j0 + col);
        }
        __syncthreads();
#pragma unroll
        for (int ks = 0; ks < 2; ++ks) {
            short8 a[2], bfr[8];
#pragma unroll
            for (int mi = 0; mi < 2; ++mi)
                a[mi] = *reinterpret_cast<const short8*>(&Ps[w * 32 + mi * 16 + fr][ks * 32 + fk]);
#pragma unroll
            for (int ni = 0; ni < 8; ++ni)
                bfr[ni] = *reinterpret_cast<const short8*>(&XTs[ni * 16 + fr][ks * 32 + fk]);
#pragma unroll
            for (int mi = 0; mi < 2; ++mi)
#pragma unroll
                for (int ni = 0; ni < 8; ++ni)
                    acc[mi][ni] = __builtin_amdgcn_mfma_f32_16x16x32_bf16(a[mi], bfr[ni], acc[mi][ni], 0, 0, 0);
        }
        __syncthreads();
    }
    // epilogue
    const float Dv = D_param[h];
    const float inv_dt = 1.f / dt;
#pragma unroll
    for (int mi = 0; mi < 2; ++mi)
#pragma unroll
        for (int ni = 0; ni < 8; ++ni) {
            int d = ni * 16 + ocol;
#pragma unroll
            for (int r = 0; r < 4; ++r) {
                int i = w * 32 + mi * 16 + orow0 + r;
                size_t idx = base + (size_t)i * 2048 + d;
                float v = bf2f(XDT[ob + (size_t)d * 128 + i]) * inv_dt;
                float yv = acc[mi][ni][r] + Dv * v;
                float g = bf2f(gateY[idx]);
                gateY[idx] = f2bf(yv * g / (1.f + expf(-g)));
            }
        }
}

extern "C" void kernel_launch(void* const* d_in, const int* in_sizes, int n_in,
                              void* d_out, int out_size, void* d_ws, size_t ws_size,
                              hipStream_t stream) {
    (void)out_size;
    static const int exp_sizes[11] = {
        NB * LSEQ * DM, NB * LSEQ * DM, 2 * DI * DM, DI * 4, DI,
        NH * DSZ * DM, NH * DSZ * DM, NH, NH, NH, DM * DI
    };
    if (n_in != 11) return;
    for (int i = 0; i < 11; ++i) if (in_sizes[i] != exp_sizes[i]) return;

    const float* x         = (const float*)d_in[0];
    const float* x_prenorm = (const float*)d_in[1];
    const float* in_proj_w = (const float*)d_in[2];
    const float* conv_w    = (const float*)d_in[3];
    const float* conv_b    = (const float*)d_in[4];
    const float* B_proj_w  = (const float*)d_in[5];
    const float* C_proj_w  = (const float*)d_in[6];
    const float* dt_bias   = (const float*)d_in[7];
    const float* A_log     = (const float*)d_in[8];
    const float* D_param   = (const float*)d_in[9];
    const float* out_proj_w= (const float*)d_in[10];
    float* out = (float*)d_out;

    const size_t NE = (size_t)NB * LSEQ * DI;     // 16,777,216 elements
    const size_t SLOT = NE * 2;                   // 32 MiB
    if (ws_size < 5 * SLOT) return;               // 160 MiB (verified available)
    char* ws = (char*)d_ws;
    bf16* S0 = (bf16*)(ws);              // value_pre -> XDT
    bf16* S1 = (bf16*)(ws + SLOT);       // gate -> y (in place)
    bf16* S2 = (bf16*)(ws + 2 * SLOT);   // vpost -> STT
    bf16* S3 = (bf16*)(ws + 3 * SLOT);   // w_in_b -> Bm -> w_out_b
    bf16* S4 = (bf16*)(ws + 4 * SLOT);   // Cm

    // d_out scratch timeline: [xb|wBb|wCb] -> BT -> P -> final f32 output
    bf16* xb  = (bf16*)d_out;
    bf16* wBb = (bf16*)((char*)d_out + 16777216);
    bf16* wCb = (bf16*)((char*)d_out + 20971520);
    bf16* wIb = S3;
    bf16* wOb = S3;
    bf16* BTg = (bf16*)d_out;            // 1024 chunks x 16384 bf16 = 33.55 MB
    bf16* Pbuf = (bf16*)d_out;

    const int M = NB * LSEQ;             // 8192
    const int NC = NB * NCHUNK * NH;     // 1024 chunk-blocks
    dim3 blk(256);

    // phase 1: in_proj (MFMA)
    cast_f2b<<<dim3(4096), blk, 0, stream>>>(x, xb, (long)NB * LSEQ * DM);
    cast_f2b<<<dim3(2048), blk, 0, stream>>>(in_proj_w, wIb, (long)2 * DI * DM);
    gemm_mfma<1, bf16><<<dim3(2 * DI / 128, M / 128), blk, 0, stream>>>(xb, wIb, S0, S1, 2 * DI, DM);
    // phase 2: conv + SiLU -> vpost (S2)
    conv_silu_kernel<<<dim3((unsigned)(NE / 256)), blk, 0, stream>>>(S0, conv_w, conv_b, S2);
    // phase 3: B/C projections (MFMA)
    cast_f2b<<<dim3(4096), blk, 0, stream>>>(x_prenorm, xb, (long)NB * LSEQ * DM);
    cast_f2b<<<dim3(1024), blk, 0, stream>>>(B_proj_w, wBb, (long)NH * DSZ * DM);
    cast_f2b<<<dim3(1024), blk, 0, stream>>>(C_proj_w, wCb, (long)NH * DSZ * DM);
    gemm_mfma<2, bf16><<<dim3(DI / 128, M / 128), blk, 0, stream>>>(xb, wBb, S3, nullptr, DI, DM);
    gemm_mfma<2, bf16><<<dim3(DI / 128, M / 128), blk, 0, stream>>>(xb, wCb, S4, nullptr, DI, DM);
    // phase 4: pre-transposes (xb/wBb/wCb dead now)
    transpose_chunk<0><<<dim3(NC), blk, 0, stream>>>(S2, S0, dt_bias, A_log);      // vpost -> XDT
    transpose_chunk<1><<<dim3(NC), blk, 0, stream>>>(S3, BTg, dt_bias, A_log);     // Bm -> BT (scaled)
    // phase 5: chunk scan (MFMA)
    chunk_statesT<<<dim3(NC), blk, 0, stream>>>(S0, BTg, S2);                      // -> STT (vpost dead)
    scan_kernel<<<dim3(NB * NH * 8), blk, 0, stream>>>(S2, dt_bias, A_log);
    chunk_cbl_mfma<<<dim3(NC), blk, 0, stream>>>(S3, S4, dt_bias, A_log, Pbuf);    // -> P (BT dead)
    chunk_y_mfma<<<dim3(NC), blk, 0, stream>>>(Pbuf, S4, S2, S0, dt_bias, A_log, D_param, S1);
    // phase 6: out_proj (MFMA) -> f32 d_out (P dead)
    cast_f2b<<<dim3(1024), blk, 0, stream>>>(out_proj_w, wOb, (long)DM * DI);
    gemm_mfma<2, float><<<dim3(DM / 128, M / 128), blk, 0, stream>>>(S1, wOb, out, nullptr, DM, DI);
}

// Round 9
// 436.965 us; speedup vs baseline: 7.6143x; 1.1245x over previous
//
#include <hip/hip_runtime.h>
#include <hip/hip_bf16.h>

// Mamba2 mixer forward, MI355X gfx950. Round 9: gemm LDS granule-XOR swizzle
// (both-sides, rule #21), merged B+C projection GEMM, vectorized conv.
// Chunk kernels frozen from round 8 (already conflict-free via +8 padding).
// Shapes fixed: B=2 L=4096 dm=1024 di=2048 H=16 ds=hd=128 cs=128
#define NB 2
#define LSEQ 4096
#define DM 1024
#define DI 2048
#define NH 16
#define DSZ 128
#define CS 128
#define NCHUNK 32

using bf16 = __hip_bfloat16;
typedef __attribute__((ext_vector_type(8))) short short8;
typedef __attribute__((ext_vector_type(4))) float f32x4;

__device__ __forceinline__ float b2f(unsigned short u) {
    union { unsigned i; float f; } c; c.i = ((unsigned)u) << 16; return c.f;
}
__device__ __forceinline__ bf16 f2bf(float v) { return __float2bfloat16(v); }
__device__ __forceinline__ float bf2f(bf16 v) { return __bfloat162float(v); }

__device__ __forceinline__ float head_dt(const float* dt_bias, int h) {
    return log1pf(expf(dt_bias[h]));               // softplus
}
__device__ __forceinline__ float head_l2dec(const float* dt_bias, const float* A_log, int h, float* dt_out) {
    float dt = head_dt(dt_bias, h);
    *dt_out = dt;
    return -expf(A_log[h]) * dt * 1.4426950408889634f;   // log2(decay)
}

__device__ __forceinline__ void storeC(bf16* C, size_t idx, float v) { C[idx] = f2bf(v); }
__device__ __forceinline__ void storeC(float* C, size_t idx, float v) { C[idx] = v; }

// async global->LDS, 16B per lane; lds base wave-uniform (HW adds lane*16B)
__device__ __forceinline__ void gload16(const bf16* g, bf16* l) {
    __builtin_amdgcn_global_load_lds(
        (const __attribute__((address_space(1))) void*)g,
        (__attribute__((address_space(3))) void*)l, 16, 0, 0);
}

// ---------------- f32 -> bf16 cast
__global__ __launch_bounds__(256) void cast_f2b(const float* __restrict__ in,
                                                bf16* __restrict__ out, long n) {
    long i = ((long)blockIdx.x * 256 + threadIdx.x) * 8;
    if (i >= n) return;
    float4 a = *reinterpret_cast<const float4*>(in + i);
    float4 b = *reinterpret_cast<const float4*>(in + i + 4);
    union { bf16 h[8]; short8 v; } o;
    o.h[0] = f2bf(a.x); o.h[1] = f2bf(a.y); o.h[2] = f2bf(a.z); o.h[3] = f2bf(a.w);
    o.h[4] = f2bf(b.x); o.h[5] = f2bf(b.y); o.h[6] = f2bf(b.z); o.h[7] = f2bf(b.w);
    *reinterpret_cast<short8*>(out + i) = o.v;
}

// ---------------- MFMA GEMM with granule-XOR LDS swizzle.
// LDS dest linear (global_load_lds); SOURCE granule pre-swizzled by ^(row&3);
// fragment READ granule swizzled by the same involution -> conflict-free.
template <int MODE, typename TO>
__global__ __launch_bounds__(256) void gemm_mfma(const bf16* __restrict__ A,
                                                 const bf16* __restrict__ W,
                                                 TO* __restrict__ C0, TO* __restrict__ C1,
                                                 int N, int K) {
    __shared__ bf16 As[2][128 * 32];
    __shared__ bf16 Ws[2][128 * 32];
    const int tid = threadIdx.x;
    const int lane = tid & 63, w = tid >> 6;
    const int wr = w >> 1, wc = w & 1;
    const int bm = blockIdx.y * 128, bn = blockIdx.x * 128;
    const int srow = lane >> 2;                                // 0..15 within row-group
    const int skoff = (((lane & 3) ^ ((lane >> 2) & 3)) * 8);  // swizzled source granule
    const int g0 = w * 2, g1 = w * 2 + 1;
    const int fr = lane & 15;
    const int fk = (((lane >> 4) ^ (lane & 3)) * 8);           // swizzled read granule
    f32x4 acc[4][4] = {};
#define STAGE(buf, kt)                                                                  \
    do {                                                                                \
        gload16(A + (size_t)(bm + g0 * 16 + srow) * K + (kt) + skoff, &As[buf][g0 * 512]); \
        gload16(A + (size_t)(bm + g1 * 16 + srow) * K + (kt) + skoff, &As[buf][g1 * 512]); \
        gload16(W + (size_t)(bn + g0 * 16 + srow) * K + (kt) + skoff, &Ws[buf][g0 * 512]); \
        gload16(W + (size_t)(bn + g1 * 16 + srow) * K + (kt) + skoff, &Ws[buf][g1 * 512]); \
    } while (0)
    STAGE(0, 0);
    __syncthreads();
    const int NT = K / 32;
    int cur = 0;
    for (int t = 0; t < NT; ++t) {
        if (t + 1 < NT) STAGE(cur ^ 1, (t + 1) * 32);
        short8 af[4], bfr[4];
#pragma unroll
        for (int mi = 0; mi < 4; ++mi)
            af[mi] = *reinterpret_cast<const short8*>(&As[cur][(wr * 64 + mi * 16 + fr) * 32 + fk]);
#pragma unroll
        for (int ni = 0; ni < 4; ++ni)
            bfr[ni] = *reinterpret_cast<const short8*>(&Ws[cur][(wc * 64 + ni * 16 + fr) * 32 + fk]);
#pragma unroll
        for (int mi = 0; mi < 4; ++mi)
#pragma unroll
            for (int ni = 0; ni < 4; ++ni)
                acc[mi][ni] = __builtin_amdgcn_mfma_f32_16x16x32_bf16(af[mi], bfr[ni], acc[mi][ni], 0, 0, 0);
        __syncthreads();
        cur ^= 1;
    }
#undef STAGE
    const int orow0 = (lane >> 4) * 4;
    const int ocol = lane & 15;
#pragma unroll
    for (int mi = 0; mi < 4; ++mi)
#pragma unroll
        for (int ni = 0; ni < 4; ++ni) {
            int col = bn + wc * 64 + ni * 16 + ocol;
#pragma unroll
            for (int r = 0; r < 4; ++r) {
                int row = bm + wr * 64 + mi * 16 + orow0 + r;
                float v = acc[mi][ni][r];
                if (MODE == 1) {
                    if (col < DI) storeC(C0, (size_t)row * DI + col, v);
                    else          storeC(C1, (size_t)row * DI + (col - DI), v);
                } else {
                    storeC(C0, (size_t)row * N + col, v);
                }
            }
        }
}

// ---------------- depthwise causal conv (K=4) + bias + SiLU, vectorized x8
__global__ __launch_bounds__(256) void conv_silu_vec(const bf16* __restrict__ vpre,
                                                     const float* __restrict__ cw,
                                                     const float* __restrict__ cb,
                                                     bf16* __restrict__ vpost) {
    size_t e = ((size_t)blockIdx.x * 256 + threadIdx.x) * 8;   // over NB*LSEQ*DI
    int c = (int)(e & (DI - 1));
    size_t bl = e >> 11;
    int l = (int)(bl & (LSEQ - 1));
    float vin[4][8];
#pragma unroll
    for (int k = 0; k < 4; ++k) {
        if (l - 3 + k >= 0) {
            short8 v = *reinterpret_cast<const short8*>(vpre + e + (long)(k - 3) * DI);
#pragma unroll
            for (int j = 0; j < 8; ++j) vin[k][j] = b2f((unsigned short)v[j]);
        } else {
#pragma unroll
            for (int j = 0; j < 8; ++j) vin[k][j] = 0.f;
        }
    }
    union { bf16 h[8]; short8 v; } o;
#pragma unroll
    for (int j = 0; j < 8; ++j) {
        float4 w4 = *reinterpret_cast<const float4*>(cw + (c + j) * 4);
        float s = cb[c + j] + w4.x * vin[0][j] + w4.y * vin[1][j] + w4.z * vin[2][j] + w4.w * vin[3][j];
        o.h[j] = f2bf(s / (1.f + expf(-s)));
    }
    *reinterpret_cast<short8*>(vpost + e) = o.v;
}

// ---------------- per-chunk 128x128 transpose (+scale). bid = (b*32+n)*16+h
template <int SCALEMODE>
__global__ __launch_bounds__(256) void transpose_chunk(const bf16* __restrict__ in, bf16* __restrict__ outp,
                                                       const float* __restrict__ dt_bias,
                                                       const float* __restrict__ A_log) {
    __shared__ bf16 Ts[128][136];
    __shared__ float dpow[128];
    const int tid = threadIdx.x;
    const int bid = blockIdx.x;
    const int h = bid & 15, bn = bid >> 4;
    float dt; float l2d = head_l2dec(dt_bias, A_log, h, &dt);
    if (SCALEMODE == 1 && tid < 128) dpow[tid] = exp2f((float)(127 - tid) * l2d);
    const size_t base = (size_t)bn * CS * 2048 + (size_t)h * 128;
    {
        const int jr = tid >> 4, c8 = (tid & 15) * 8;
        for (int j0 = 0; j0 < 128; j0 += 16)
            *reinterpret_cast<short8*>(&Ts[j0 + jr][c8]) =
                *reinterpret_cast<const short8*>(in + base + (size_t)(j0 + jr) * 2048 + c8);
    }
    __syncthreads();
    const size_t ob = (size_t)bid * 16384;
    const int d = tid & 127;
    for (int jg = (tid >> 7); jg < 16; jg += 2) {
        int j0 = jg * 8;
        union { bf16 h8[8]; short8 v; } o;
#pragma unroll
        for (int e = 0; e < 8; ++e) {
            float val = bf2f(Ts[j0 + e][d]);
            val *= (SCALEMODE == 1) ? dpow[j0 + e] : dt;
            o.h8[e] = f2bf(val);
        }
        *reinterpret_cast<short8*>(outp + ob + (size_t)d * 128 + j0) = o.v;
    }
}

// ---------------- K1: STT[d][s] = sum_j XDT[d][j] * BT[s][j]  (MFMA, per chunk)
__global__ __launch_bounds__(256) void chunk_statesT(const bf16* __restrict__ XDT,
                                                     const bf16* __restrict__ BTg,
                                                     bf16* __restrict__ STT) {
    __shared__ bf16 XTs[128][72];
    __shared__ bf16 BTs[128][72];
    const int tid = threadIdx.x;
    const size_t ob = (size_t)blockIdx.x * 16384;
    const int lane = tid & 63, w = tid >> 6;
    const int fr = lane & 15, fk = (lane >> 4) * 8;
    f32x4 acc[2][8] = {};
    for (int j0 = 0; j0 < 128; j0 += 64) {
        for (int rr = 0; rr < 128; rr += 32) {
            int row = rr + (tid >> 3);
            int col = (tid & 7) * 8;
            *reinterpret_cast<short8*>(&XTs[row][col]) =
                *reinterpret_cast<const short8*>(XDT + ob + (size_t)row * 128 + j0 + col);
            *reinterpret_cast<short8*>(&BTs[row][col]) =
                *reinterpret_cast<const short8*>(BTg + ob + (size_t)row * 128 + j0 + col);
        }
        __syncthreads();
#pragma unroll
        for (int ks = 0; ks < 2; ++ks) {
            short8 a[2], bfr[8];
#pragma unroll
            for (int mi = 0; mi < 2; ++mi)
                a[mi] = *reinterpret_cast<const short8*>(&XTs[w * 32 + mi * 16 + fr][ks * 32 + fk]);
#pragma unroll
            for (int ni = 0; ni < 8; ++ni)
                bfr[ni] = *reinterpret_cast<const short8*>(&BTs[ni * 16 + fr][ks * 32 + fk]);
#pragma unroll
            for (int mi = 0; mi < 2; ++mi)
#pragma unroll
                for (int ni = 0; ni < 8; ++ni)
                    acc[mi][ni] = __builtin_amdgcn_mfma_f32_16x16x32_bf16(a[mi], bfr[ni], acc[mi][ni], 0, 0, 0);
        }
        __syncthreads();
    }
    const int orow0 = (lane >> 4) * 4, ocol = lane & 15;
#pragma unroll
    for (int mi = 0; mi < 2; ++mi)
#pragma unroll
        for (int ni = 0; ni < 8; ++ni) {
            int s = ni * 16 + ocol;
#pragma unroll
            for (int r = 0; r < 4; ++r) {
                int d = w * 32 + mi * 16 + orow0 + r;
                STT[ob + (size_t)d * 128 + s] = f2bf(acc[mi][ni][r]);
            }
        }
}

// ---------------- inter-chunk recurrence on STT (merged batches), in place
__global__ __launch_bounds__(256) void scan_kernel(bf16* __restrict__ ST,
                                                   const float* __restrict__ dt_bias,
                                                   const float* __restrict__ A_log) {
    const int q = blockIdx.x & 7;
    const int h = (blockIdx.x >> 3) & 15;
    const int b = blockIdx.x >> 7;
    float dt; float l2d = head_l2dec(dt_bias, A_log, h, &dt);
    float cd = exp2f(128.f * l2d);
    const int tid = threadIdx.x;
    float r[8] = {};
    for (int n = 0; n < NCHUNK; ++n) {
        size_t base = ((size_t)((b * NCHUNK + n) * NH + h)) * 16384 + (size_t)q * 2048;
#pragma unroll
        for (int e = 0; e < 8; ++e) {
            size_t idx = base + e * 256 + tid;
            float v = bf2f(ST[idx]);
            ST[idx] = f2bf(r[e]);
            r[e] = cd * r[e] + v;
        }
    }
}

// ---------------- K2a: P[i][j] = (i>=j)? dec^(i-j) * sum_s C[i,s]*B[j,s] : 0
__global__ __launch_bounds__(256) void chunk_cbl_mfma(const bf16* __restrict__ Bm, const bf16* __restrict__ Cm,
                                                      const float* __restrict__ dt_bias,
                                                      const float* __restrict__ A_log,
                                                      bf16* __restrict__ P) {
    __shared__ bf16 Cs[128][72];
    __shared__ bf16 Bs[128][72];
    const int tid = threadIdx.x;
    const int bid = blockIdx.x;
    const int h = bid & 15, bn = bid >> 4;
    float dt; float l2d = head_l2dec(dt_bias, A_log, h, &dt);
    const size_t base = (size_t)bn * CS * 2048 + (size_t)h * 128;
    const int lane = tid & 63, w = tid >> 6;
    const int fr = lane & 15, fk = (lane >> 4) * 8;
    f32x4 acc[2][8] = {};
    for (int s0 = 0; s0 < 128; s0 += 64) {
        for (int rr = 0; rr < 128; rr += 32) {
            int row = rr + (tid >> 3);
            int col = (tid & 7) * 8;
            *reinterpret_cast<short8*>(&Cs[row][col]) =
                *reinterpret_cast<const short8*>(Cm + base + (size_t)row * 2048 + s0 + col);
            *reinterpret_cast<short8*>(&Bs[row][col]) =
                *reinterpret_cast<const short8*>(Bm + base + (size_t)row * 2048 + s0 + col);
        }
        __syncthreads();
#pragma unroll
        for (int ks = 0; ks < 2; ++ks) {
            short8 a[2], bfr[8];
#pragma unroll
            for (int mi = 0; mi < 2; ++mi)
                a[mi] = *reinterpret_cast<const short8*>(&Cs[w * 32 + mi * 16 + fr][ks * 32 + fk]);
#pragma unroll
            for (int ni = 0; ni < 8; ++ni)
                bfr[ni] = *reinterpret_cast<const short8*>(&Bs[ni * 16 + fr][ks * 32 + fk]);
#pragma unroll
            for (int mi = 0; mi < 2; ++mi)
#pragma unroll
                for (int ni = 0; ni < 8; ++ni)
                    acc[mi][ni] = __builtin_amdgcn_mfma_f32_16x16x32_bf16(a[mi], bfr[ni], acc[mi][ni], 0, 0, 0);
        }
        __syncthreads();
    }
    const size_t ob = (size_t)bid * 16384;
    const int orow0 = (lane >> 4) * 4, ocol = lane & 15;
#pragma unroll
    for (int mi = 0; mi < 2; ++mi)
#pragma unroll
        for (int ni = 0; ni < 8; ++ni) {
            int j = ni * 16 + ocol;
#pragma unroll
            for (int r = 0; r < 4; ++r) {
                int i = w * 32 + mi * 16 + orow0 + r;
                float v = (i >= j) ? acc[mi][ni][r] * exp2f((float)(i - j) * l2d) : 0.f;
                P[ob + (size_t)i * 128 + j] = f2bf(v);
            }
        }
}

// ---------------- K2b: y = P@xdt + (C@h^T)*dec^(i+1) + D*v, *silu(gate)
__global__ __launch_bounds__(256) void chunk_y_mfma(const bf16* __restrict__ P, const bf16* __restrict__ Cm,
                                                    const bf16* __restrict__ STT, const bf16* __restrict__ XDT,
                                                    const float* __restrict__ dt_bias,
                                                    const float* __restrict__ A_log,
                                                    const float* __restrict__ D_param,
                                                    bf16* __restrict__ gateY) {
    __shared__ bf16 Ps[128][72];
    __shared__ bf16 XTs[128][72];
    const int tid = threadIdx.x;
    const int bid = blockIdx.x;
    const int h = bid & 15, bn = bid >> 4;
    float dt; float l2d = head_l2dec(dt_bias, A_log, h, &dt);
    const size_t base = (size_t)bn * CS * 2048 + (size_t)h * 128;
    const size_t ob = (size_t)bid * 16384;
    const int lane = tid & 63, w = tid >> 6;
    const int fr = lane & 15, fk = (lane >> 4) * 8;
    const int orow0 = (lane >> 4) * 4, ocol = lane & 15;
    f32x4 acc[2][8] = {};
#pragma unroll
    for (int ks = 0; ks < 4; ++ks) {
        short8 a[2], bfr[8];
#pragma unroll
        for (int mi = 0; mi < 2; ++mi)
            a[mi] = *reinterpret_cast<const short8*>(Cm + base + (size_t)(w * 32 + mi * 16 + fr) * 2048 + ks * 32 + fk);
#pragma unroll
        for (int ni = 0; ni < 8; ++ni)
            bfr[ni] = *reinterpret_cast<const short8*>(STT + ob + (size_t)(ni * 16 + fr) * 128 + ks * 32 + fk);
#pragma unroll
        for (int mi = 0; mi < 2; ++mi)
#pragma unroll
            for (int ni = 0; ni < 8; ++ni)
                acc[mi][ni] = __builtin_amdgcn_mfma_f32_16x16x32_bf16(a[mi], bfr[ni], acc[mi][ni], 0, 0, 0);
    }
#pragma unroll
    for (int mi = 0; mi < 2; ++mi)
#pragma unroll
        for (int r = 0; r < 4; ++r) {
            int i = w * 32 + mi * 16 + orow0 + r;
            float sc = exp2f((float)(i + 1) * l2d);
#pragma unroll
            for (int ni = 0; ni < 8; ++ni) acc[mi][ni][r] *= sc;
        }
    for (int j0 = 0; j0 < 128; j0 += 64) {
        for (int rr = 0; rr < 128; rr += 32) {
            int row = rr + (tid >> 3);
            int col = (tid & 7) * 8;
            *reinterpret_cast<short8*>(&Ps[row][col]) =
                *reinterpret_cast<const short8*>(P + ob + (size_t)row * 128 + j0 + col);
            *reinterpret_cast<short8*>(&XTs[row][col]) =
                *reinterpret_cast<const short8*>(XDT + ob + (size_t)row * 128 + j0 + col);
        }
        __syncthreads();
#pragma unroll
        for (int ks = 0; ks < 2; ++ks) {
            short8 a[2], bfr[8];
#pragma unroll
            for (int mi = 0; mi < 2; ++mi)
                a[mi] = *reinterpret_cast<const short8*>(&Ps[w * 32 + mi * 16 + fr][ks * 32 + fk]);
#pragma unroll
            for (int ni = 0; ni < 8; ++ni)
                bfr[ni] = *reinterpret_cast<const short8*>(&XTs[ni * 16 + fr][ks * 32 + fk]);
#pragma unroll
            for (int mi = 0; mi < 2; ++mi)
#pragma unroll
                for (int ni = 0; ni < 8; ++ni)
                    acc[mi][ni] = __builtin_amdgcn_mfma_f32_16x16x32_bf16(a[mi], bfr[ni], acc[mi][ni], 0, 0, 0);
        }
        __syncthreads();
    }
    const float Dv = D_param[h];
    const float inv_dt = 1.f / dt;
#pragma unroll
    for (int mi = 0; mi < 2; ++mi)
#pragma unroll
        for (int ni = 0; ni < 8; ++ni) {
            int d = ni * 16 + ocol;
#pragma unroll
            for (int r = 0; r < 4; ++r) {
                int i = w * 32 + mi * 16 + orow0 + r;
                size_t idx = base + (size_t)i * 2048 + d;
                float v = bf2f(XDT[ob + (size_t)d * 128 + i]) * inv_dt;
                float yv = acc[mi][ni][r] + Dv * v;
                float g = bf2f(gateY[idx]);
                gateY[idx] = f2bf(yv * g / (1.f + expf(-g)));
            }
        }
}

extern "C" void kernel_launch(void* const* d_in, const int* in_sizes, int n_in,
                              void* d_out, int out_size, void* d_ws, size_t ws_size,
                              hipStream_t stream) {
    (void)out_size;
    static const int exp_sizes[11] = {
        NB * LSEQ * DM, NB * LSEQ * DM, 2 * DI * DM, DI * 4, DI,
        NH * DSZ * DM, NH * DSZ * DM, NH, NH, NH, DM * DI
    };
    if (n_in != 11) return;
    for (int i = 0; i < 11; ++i) if (in_sizes[i] != exp_sizes[i]) return;

    const float* x         = (const float*)d_in[0];
    const float* x_prenorm = (const float*)d_in[1];
    const float* in_proj_w = (const float*)d_in[2];
    const float* conv_w    = (const float*)d_in[3];
    const float* conv_b    = (const float*)d_in[4];
    const float* B_proj_w  = (const float*)d_in[5];
    const float* C_proj_w  = (const float*)d_in[6];
    const float* dt_bias   = (const float*)d_in[7];
    const float* A_log     = (const float*)d_in[8];
    const float* D_param   = (const float*)d_in[9];
    const float* out_proj_w= (const float*)d_in[10];
    float* out = (float*)d_out;

    const size_t NE = (size_t)NB * LSEQ * DI;     // 16,777,216 elements
    const size_t SLOT = NE * 2;                   // 32 MiB
    if (ws_size < 5 * SLOT) return;               // 160 MiB (verified available)
    char* ws = (char*)d_ws;
    bf16* S0 = (bf16*)(ws);              // value_pre -> XDT
    bf16* S1 = (bf16*)(ws + SLOT);       // gate -> y (in place)
    bf16* S2 = (bf16*)(ws + 2 * SLOT);   // vpost -> STT
    bf16* S3 = (bf16*)(ws + 3 * SLOT);   // w_in_b -> Bm -> w_out_b
    bf16* S4 = (bf16*)(ws + 4 * SLOT);   // Cm

    // d_out scratch timeline: [xb | wBCb] -> BT -> P -> final f32 output
    bf16* xb   = (bf16*)d_out;                         // 16.8 MB
    bf16* wBCb = (bf16*)((char*)d_out + 16777216);     // 8.4 MB (B|C weights concat)
    bf16* wIb = S3;
    bf16* wOb = S3;
    bf16* BTg = (bf16*)d_out;
    bf16* Pbuf = (bf16*)d_out;

    const int M = NB * LSEQ;             // 8192
    const int NC = NB * NCHUNK * NH;     // 1024 chunk-blocks
    dim3 blk(256);

    // phase 1: in_proj (MFMA)
    cast_f2b<<<dim3(4096), blk, 0, stream>>>(x, xb, (long)NB * LSEQ * DM);
    cast_f2b<<<dim3(2048), blk, 0, stream>>>(in_proj_w, wIb, (long)2 * DI * DM);
    gemm_mfma<1, bf16><<<dim3(2 * DI / 128, M / 128), blk, 0, stream>>>(xb, wIb, S0, S1, 2 * DI, DM);
    // phase 2: conv + SiLU -> vpost (S2), vectorized
    conv_silu_vec<<<dim3((unsigned)(NE / 2048)), blk, 0, stream>>>(S0, conv_w, conv_b, S2);
    // phase 3: merged B+C projection (MFMA, one pass over x_prenorm)
    cast_f2b<<<dim3(4096), blk, 0, stream>>>(x_prenorm, xb, (long)NB * LSEQ * DM);
    cast_f2b<<<dim3(1024), blk, 0, stream>>>(B_proj_w, wBCb, (long)NH * DSZ * DM);
    cast_f2b<<<dim3(1024), blk, 0, stream>>>(C_proj_w, wBCb + (size_t)NH * DSZ * DM, (long)NH * DSZ * DM);
    gemm_mfma<1, bf16><<<dim3(2 * DI / 128, M / 128), blk, 0, stream>>>(xb, wBCb, S3, S4, 2 * DI, DM);
    // phase 4: pre-transposes (xb/wBCb dead now)
    transpose_chunk<0><<<dim3(NC), blk, 0, stream>>>(S2, S0, dt_bias, A_log);      // vpost -> XDT
    transpose_chunk<1><<<dim3(NC), blk, 0, stream>>>(S3, BTg, dt_bias, A_log);     // Bm -> BT (scaled)
    // phase 5: chunk scan (MFMA)
    chunk_statesT<<<dim3(NC), blk, 0, stream>>>(S0, BTg, S2);                      // -> STT (vpost dead)
    scan_kernel<<<dim3(NB * NH * 8), blk, 0, stream>>>(S2, dt_bias, A_log);
    chunk_cbl_mfma<<<dim3(NC), blk, 0, stream>>>(S3, S4, dt_bias, A_log, Pbuf);    // -> P (BT dead)
    chunk_y_mfma<<<dim3(NC), blk, 0, stream>>>(Pbuf, S4, S2, S0, dt_bias, A_log, D_param, S1);
    // phase 6: out_proj (MFMA) -> f32 d_out (P dead)
    cast_f2b<<<dim3(1024), blk, 0, stream>>>(out_proj_w, wOb, (long)DM * DI);
    gemm_mfma<2, float><<<dim3(DM / 128, M / 128), blk, 0, stream>>>(S1, wOb, out, nullptr, DM, DI);
}